// Round 1
// baseline (282.644 us; speedup 1.0000x reference)
//
#include <hip/hip_runtime.h>

#define NC 5
#define DICE_EPS 1e-7f

// Workspace layout: 15 counters, each padded to its own 64B cacheline.
// cnt[c*16]        : den1[c] = count(pred == c)
// cnt[(5+c)*16]    : den2[c] = count(mask == c)
// cnt[(10+c)*16]   : num[c]  = count(pred == c && mask == c)

__global__ __launch_bounds__(256) void dice_hist_kernel(
    const float* __restrict__ pred_f, const int* __restrict__ mask,
    unsigned int* __restrict__ cnt, int n)
{
    unsigned int den1[NC] = {0, 0, 0, 0, 0};
    unsigned int den2[NC] = {0, 0, 0, 0, 0};
    unsigned int num [NC] = {0, 0, 0, 0, 0};

    const int n4 = n >> 2;
    const int tid = blockIdx.x * blockDim.x + threadIdx.x;
    const int stride = gridDim.x * blockDim.x;

    const float4* __restrict__ p4 = (const float4*)pred_f;
    const int4*   __restrict__ m4 = (const int4*)mask;

    for (int i = tid; i < n4; i += stride) {
        float4 pf = p4[i];
        int4   mv = m4[i];
        int p0 = (int)pf.x, p1 = (int)pf.y, p2 = (int)pf.z, p3 = (int)pf.w;
        #pragma unroll
        for (int c = 0; c < NC; ++c) {
            unsigned int a0 = (p0 == c), a1 = (p1 == c), a2 = (p2 == c), a3 = (p3 == c);
            unsigned int b0 = (mv.x == c), b1 = (mv.y == c), b2 = (mv.z == c), b3 = (mv.w == c);
            den1[c] += a0 + a1 + a2 + a3;
            den2[c] += b0 + b1 + b2 + b3;
            num [c] += (a0 & b0) + (a1 & b1) + (a2 & b2) + (a3 & b3);
        }
    }
    // scalar tail (n is a multiple of 4 for this problem, but be safe)
    for (int i = (n4 << 2) + tid; i < n; i += stride) {
        int p = (int)pred_f[i];
        int m = mask[i];
        #pragma unroll
        for (int c = 0; c < NC; ++c) {
            unsigned int a = (p == c), b = (m == c);
            den1[c] += a;
            den2[c] += b;
            num [c] += a & b;
        }
    }

    // wave-level butterfly reduce (wave = 64 lanes)
    #pragma unroll
    for (int c = 0; c < NC; ++c) {
        #pragma unroll
        for (int off = 32; off > 0; off >>= 1) {
            den1[c] += __shfl_down(den1[c], off, 64);
            den2[c] += __shfl_down(den2[c], off, 64);
            num [c] += __shfl_down(num [c], off, 64);
        }
    }

    __shared__ unsigned int s_cnt[3 * NC];
    if (threadIdx.x < 3 * NC) s_cnt[threadIdx.x] = 0;
    __syncthreads();

    const int lane = threadIdx.x & 63;
    if (lane == 0) {
        #pragma unroll
        for (int c = 0; c < NC; ++c) {
            atomicAdd(&s_cnt[c],          den1[c]);
            atomicAdd(&s_cnt[NC + c],     den2[c]);
            atomicAdd(&s_cnt[2 * NC + c], num [c]);
        }
    }
    __syncthreads();

    if (threadIdx.x < 3 * NC) {
        atomicAdd(&cnt[threadIdx.x * 16], s_cnt[threadIdx.x]);
    }
}

__global__ void dice_final_kernel(const unsigned int* __restrict__ cnt,
                                  float* __restrict__ out)
{
    if (blockIdx.x == 0 && threadIdx.x == 0) {
        float s = 0.0f;
        #pragma unroll
        for (int c = 0; c < NC; ++c) {
            float d1 = (float)cnt[c * 16];
            float d2 = (float)cnt[(NC + c) * 16];
            float nm = (float)cnt[(2 * NC + c) * 16];
            s += 2.0f * ((nm + DICE_EPS) / (d1 + d2 + DICE_EPS));
        }
        out[0] = s / (float)NC;
    }
}

extern "C" void kernel_launch(void* const* d_in, const int* in_sizes, int n_in,
                              void* d_out, int out_size, void* d_ws, size_t ws_size,
                              hipStream_t stream) {
    const float* pred = (const float*)d_in[0];   // "output": float32 labels
    const int*   mask = (const int*)d_in[1];     // "mask": int32 labels
    const int n = in_sizes[0];                   // 128*512*512 = 33,554,432

    unsigned int* cnt = (unsigned int*)d_ws;
    hipMemsetAsync(d_ws, 0, 3 * NC * 16 * sizeof(unsigned int), stream);

    const int threads = 256;
    const int blocks = 1024;   // 32 float4-iters/thread; 16 waves/CU
    dice_hist_kernel<<<blocks, threads, 0, stream>>>(pred, mask, cnt, n);
    dice_final_kernel<<<1, 64, 0, stream>>>(cnt, (float*)d_out);
}